// Round 2
// baseline (342.832 us; speedup 1.0000x reference)
//
#include <hip/hip_runtime.h>
#include <hip/hip_bf16.h>
#include <stdint.h>

// Shapes (fixed): B=4, N=8, Q=256, K=1024, D_MODEL=512, H=8, Dh=64, R=8, sigma=0.05

typedef __attribute__((ext_vector_type(8))) short bf16x8;
typedef __attribute__((ext_vector_type(4))) float f32x4;

__device__ __forceinline__ unsigned short f2b(float f){
    unsigned int u = __builtin_bit_cast(unsigned int, f);
    unsigned int r = u + 0x7fffu + ((u >> 16) & 1u);   // RNE
    return (unsigned short)(r >> 16);
}

// XOR swizzle for 64-col bf16 LDS tiles (128B rows): row-wise b128 fragment
// reads and staging writes are conflict-free.
__device__ __forceinline__ int swz(int row, int byteInRow){
    return row*128 + (byteInRow ^ ((row & 7) << 4));
}
// Two-level swizzle for transpose tiles: conflict-free on row-writes AND
// column-reads (XOR varies with both row&7 and row>>3).
__device__ __forceinline__ int swzT(int row, int byteInRow){
    return row*128 + (byteInRow ^ (((row ^ (row >> 3)) & 7) << 4));
}

// ---------------- weight transpose + bf16 convert: Wt[n][k] = W[k][n] -------
__global__ __launch_bounds__(256) void wt_kernel(const float* __restrict__ W,
                                                 unsigned short* __restrict__ Wt){
    __shared__ float tile[64][65];
    int kt = blockIdx.x, nt = blockIdx.y;
    int tid = threadIdx.x;
    #pragma unroll
    for(int it=0; it<16; ++it){
        int idx = it*256 + tid;
        int r = idx >> 6, c = idx & 63;
        tile[r][c] = W[(kt*64 + r)*512 + nt*64 + c];
    }
    __syncthreads();
    #pragma unroll
    for(int it=0; it<16; ++it){
        int idx = it*256 + tid;
        int r = idx >> 6, c = idx & 63;
        Wt[(nt*64 + r)*512 + kt*64 + c] = f2b(tile[c][r]);
    }
}

// ---------------- positional bias: bias[b][q][k] ----------------------------
__global__ __launch_bounds__(256) void bias_kernel(
    const float* __restrict__ qpos, const float* __restrict__ kpos,
    const float* __restrict__ Wqb, const float* __restrict__ Wkb,
    float* __restrict__ out){
    int id = blockIdx.x*256 + threadIdx.x;   // [4][256][1024]
    int b = id >> 18;
    int q = (id >> 10) & 255;
    int k = id & 1023;
    const float* q3 = qpos + (b*256 + q)*3;
    const float* k3 = kpos + (b*1024 + k)*3;
    float qx=q3[0], qy=q3[1], qz=q3[2];
    float kx=k3[0], ky=k3[1], kz=k3[2];
    float dx=qx-kx, dy=qy-ky, dz=qz-kz;
    float dist2 = dx*dx + dy*dy + dz*dz;
    float lf = 0.f;
    #pragma unroll
    for(int r=0;r<8;++r){
        float qb = qx*Wqb[r] + qy*Wqb[8+r] + qz*Wqb[16+r];
        float kb = kx*Wkb[r] + ky*Wkb[8+r] + kz*Wkb[16+r];
        lf += qb*kb;
    }
    out[id] = -dist2*200.0f + lf*0.35355339059327373f;
}

// ---------------- GEMM: C[M][512] = A(f32)[M][512] @ W[512][512] + bias -----
template<bool OUT_BF16>
__global__ __launch_bounds__(256) void gemm512(
    const float* __restrict__ A,
    const unsigned short* __restrict__ Bt,
    const float* __restrict__ bias,
    void* __restrict__ Cv){
    __shared__ alignas(16) char sm[32768];
    char* As = sm;
    char* Bs = sm + 16384;
    int m0 = blockIdx.x * 128, n0 = blockIdx.y * 128;
    int tid = threadIdx.x;
    int l = tid & 63, wid = tid >> 6;
    int wr = wid >> 1, wc = wid & 1;
    int l15 = l & 15, lg = l >> 4;

    f32x4 acc[4][4];
    const f32x4 z4 = {0.f,0.f,0.f,0.f};
    #pragma unroll
    for(int m=0;m<4;++m)
        #pragma unroll
        for(int n=0;n<4;++n) acc[m][n] = z4;

    for(int kt=0; kt<8; ++kt){
        int k0 = kt*64;
        __syncthreads();
        #pragma unroll
        for(int it=0; it<8; ++it){
            int idx = it*256 + tid;          // float4 index
            int row = idx >> 4;
            int col = (idx & 15) * 4;
            float4 v = *reinterpret_cast<const float4*>(A + (m0+row)*512 + k0 + col);
            uint2 d;
            d.x = (unsigned)f2b(v.x) | ((unsigned)f2b(v.y) << 16);
            d.y = (unsigned)f2b(v.z) | ((unsigned)f2b(v.w) << 16);
            *reinterpret_cast<uint2*>(As + swz(row, col*2)) = d;
        }
        #pragma unroll
        for(int it=0; it<4; ++it){
            int idx = it*256 + tid;          // 16B chunk index
            int row = idx >> 3;
            int colb = (idx & 7) * 16;
            uint4 v = *reinterpret_cast<const uint4*>(Bt + (n0+row)*512 + k0 + colb/2);
            *reinterpret_cast<uint4*>(Bs + swz(row, colb)) = v;
        }
        __syncthreads();
        #pragma unroll
        for(int kk=0; kk<2; ++kk){
            bf16x8 af[4], bfr[4];
            #pragma unroll
            for(int m=0;m<4;++m)
                af[m] = *reinterpret_cast<const bf16x8*>(As + swz(wr*64 + m*16 + l15, kk*64 + lg*16));
            #pragma unroll
            for(int n=0;n<4;++n)
                bfr[n] = *reinterpret_cast<const bf16x8*>(Bs + swz(wc*64 + n*16 + l15, kk*64 + lg*16));
            #pragma unroll
            for(int m=0;m<4;++m)
                #pragma unroll
                for(int n=0;n<4;++n)
                    acc[m][n] = __builtin_amdgcn_mfma_f32_16x16x32_bf16(af[m], bfr[n], acc[m][n], 0, 0, 0);
        }
    }
    #pragma unroll
    for(int m=0;m<4;++m){
        int row = m0 + wr*64 + m*16 + lg*4;
        #pragma unroll
        for(int n=0;n<4;++n){
            int col = n0 + wc*64 + n*16 + l15;
            float bv = bias[col];
            #pragma unroll
            for(int j=0;j<4;++j){
                float val = acc[m][n][j] + bv;
                if(OUT_BF16)
                    reinterpret_cast<unsigned short*>(Cv)[(size_t)(row+j)*512 + col] = f2b(val);
                else
                    reinterpret_cast<float*>(Cv)[(size_t)(row+j)*512 + col] = val;
            }
        }
    }
}

// ---------------- V transpose: vp[z*1024+k][h*64+d] -> vpT[(z*8+h)*64+d][k] -
__global__ __launch_bounds__(256) void vt_kernel(const unsigned short* __restrict__ vp,
                                                 unsigned short* __restrict__ vpT){
    __shared__ alignas(16) char sm[8192];   // 64 rows x 128B, swzT layout
    int kt = blockIdx.x, h = blockIdx.y, z = blockIdx.z;
    int tid = threadIdx.x;
    #pragma unroll
    for(int it=0; it<2; ++it){
        int idx = it*256 + tid;
        int r = idx >> 3;        // k within tile
        int c8 = idx & 7;        // d block
        uint4 v = *reinterpret_cast<const uint4*>(vp + (size_t)(z*1024 + kt*64 + r)*512 + h*64 + c8*8);
        *reinterpret_cast<uint4*>(sm + swzT(r, c8*16)) = v;
    }
    __syncthreads();
    #pragma unroll
    for(int it=0; it<2; ++it){
        int idx = it*256 + tid;
        int d = idx >> 3;        // output row (d)
        int k8 = idx & 7;        // k block
        unsigned short e[8];
        #pragma unroll
        for(int j=0;j<8;++j)
            e[j] = *reinterpret_cast<const unsigned short*>(sm + swzT(k8*8+j, d*2));
        *reinterpret_cast<uint4*>(vpT + (size_t)((z*8+h)*64 + d)*1024 + kt*64 + k8*8) = *reinterpret_cast<uint4*>(e);
    }
}

// ---------------- flash attention: per (b,n,h,q-tile64) ---------------------
__global__ __launch_bounds__(256) void attn_kernel(
    const unsigned short* __restrict__ qp,   // [8192][512] bf16
    const unsigned short* __restrict__ kp,   // [32768][512] bf16
    const unsigned short* __restrict__ vpT,  // [(z*8+h)*64+d][1024] bf16
    const float* __restrict__ biasb,         // [4][256][1024]
    const int* __restrict__ mask,            // [4][1024]
    float* __restrict__ ctx){                // [8192][512] f32
    __shared__ alignas(16) char sm[24576];
    char* Ks  = sm;            // [64 kpos][64 d] bf16 swizzled
    char* VTs = sm + 8192;     // [64 d][64 kpos] bf16 swizzled
    char* Ps  = sm + 16384;    // per-wave 2048B: [16 q][64 kpos] bf16 swizzled

    int qt = blockIdx.x, h = blockIdx.y, zidx = blockIdx.z;  // z = b*8+n
    int b = zidx >> 3;
    int tid = threadIdx.x, l = tid & 63, wid = tid >> 6;
    int l15 = l & 15, lg = l >> 4;

    // Q fragments hoisted from global
    int qrow = zidx*256 + qt*64 + wid*16 + l15;
    bf16x8 qf[2];
    #pragma unroll
    for(int kk=0;kk<2;++kk)
        qf[kk] = *reinterpret_cast<const bf16x8*>(qp + (size_t)qrow*512 + h*64 + kk*32 + lg*8);

    // staging coords + bases
    int srow = tid >> 3;          // 0..31 (it adds 32)
    int sc8  = tid & 7;
    const unsigned short* kbase = kp  + (size_t)(zidx*1024)*512 + h*64;
    const unsigned short* vbase = vpT + (size_t)((zidx*8 + h)*64)*1024;

    float mrun[4], lrun[4];
    f32x4 acc[4];
    const f32x4 z4 = {0.f,0.f,0.f,0.f};
    #pragma unroll
    for(int j=0;j<4;++j){ mrun[j] = -3.0e38f; lrun[j] = 0.f; }
    #pragma unroll
    for(int t=0;t<4;++t) acc[t] = z4;

    // prefetch tile 0
    uint4 kreg[2], vreg[2];
    #pragma unroll
    for(int it=0; it<2; ++it){
        int row = it*32 + srow;
        kreg[it] = *reinterpret_cast<const uint4*>(kbase + (size_t)row*512  + sc8*8);
        vreg[it] = *reinterpret_cast<const uint4*>(vbase + (size_t)row*1024 + sc8*8);
    }

    for(int kt=0; kt<16; ++kt){
        __syncthreads();                       // compute of kt-1 done reading LDS
        #pragma unroll
        for(int it=0; it<2; ++it){
            int row = it*32 + srow;
            *reinterpret_cast<uint4*>(Ks  + swz(row, sc8*16)) = kreg[it];
            *reinterpret_cast<uint4*>(VTs + swz(row, sc8*16)) = vreg[it];
        }
        __syncthreads();
        if(kt < 15){                           // prefetch kt+1 (hides under compute)
            #pragma unroll
            for(int it=0; it<2; ++it){
                int row = it*32 + srow;
                kreg[it] = *reinterpret_cast<const uint4*>(kbase + (size_t)((kt+1)*64 + row)*512 + sc8*8);
                vreg[it] = *reinterpret_cast<const uint4*>(vbase + (size_t)row*1024 + (kt+1)*64 + sc8*8);
            }
        }

        // S = q @ K^T
        f32x4 s[4];
        #pragma unroll
        for(int t=0;t<4;++t){
            s[t] = z4;
            #pragma unroll
            for(int kk=0;kk<2;++kk){
                bf16x8 kf = *reinterpret_cast<const bf16x8*>(Ks + swz(t*16 + l15, kk*64 + lg*16));
                s[t] = __builtin_amdgcn_mfma_f32_16x16x32_bf16(qf[kk], kf, s[t], 0, 0, 0);
            }
        }
        // scale + bias + mask
        int qg = b*256 + qt*64 + wid*16 + lg*4;
        #pragma unroll
        for(int t=0;t<4;++t){
            int kcol = kt*64 + t*16 + l15;
            int mk = mask[b*1024 + kcol];
            #pragma unroll
            for(int j=0;j<4;++j){
                float bvv = biasb[(size_t)(qg + j)*1024 + kcol];
                s[t][j] = mk ? (s[t][j]*0.125f + bvv) : -10000.0f;
            }
        }
        // online softmax
        float pmax[4];
        #pragma unroll
        for(int j=0;j<4;++j){
            float mx = fmaxf(fmaxf(s[0][j], s[1][j]), fmaxf(s[2][j], s[3][j]));
            mx = fmaxf(mx, __shfl_xor(mx, 1, 16));
            mx = fmaxf(mx, __shfl_xor(mx, 2, 16));
            mx = fmaxf(mx, __shfl_xor(mx, 4, 16));
            mx = fmaxf(mx, __shfl_xor(mx, 8, 16));
            pmax[j] = mx;
        }
        float scl[4];
        #pragma unroll
        for(int j=0;j<4;++j){
            float mn = fmaxf(mrun[j], pmax[j]);
            scl[j] = __expf(mrun[j] - mn);
            mrun[j] = mn;
        }
        float psum[4] = {0.f,0.f,0.f,0.f};
        unsigned short pb[4][4];
        #pragma unroll
        for(int t=0;t<4;++t)
            #pragma unroll
            for(int j=0;j<4;++j){
                float p = __expf(s[t][j] - mrun[j]);
                psum[j] += p;
                pb[t][j] = f2b(p);
            }
        #pragma unroll
        for(int j=0;j<4;++j){
            float ps = psum[j];
            ps += __shfl_xor(ps, 1, 16);
            ps += __shfl_xor(ps, 2, 16);
            ps += __shfl_xor(ps, 4, 16);
            ps += __shfl_xor(ps, 8, 16);
            lrun[j] = lrun[j]*scl[j] + ps;
            #pragma unroll
            for(int t=0;t<4;++t) acc[t][j] *= scl[j];
        }
        // P (C-layout) -> per-wave LDS (no block barrier needed: wave-local)
        char* Pw = Ps + wid*2048;
        #pragma unroll
        for(int t=0;t<4;++t)
            #pragma unroll
            for(int j=0;j<4;++j)
                *reinterpret_cast<unsigned short*>(Pw + swz(lg*4 + j, (t*16 + l15)*2)) = pb[t][j];
        // PV: acc[t] += P @ V
        #pragma unroll
        for(int kk=0;kk<2;++kk){
            bf16x8 pf = *reinterpret_cast<const bf16x8*>(Pw + swz(l15, kk*64 + lg*16));
            #pragma unroll
            for(int t=0;t<4;++t){
                bf16x8 vf = *reinterpret_cast<const bf16x8*>(VTs + swz(t*16 + l15, kk*64 + lg*16));
                acc[t] = __builtin_amdgcn_mfma_f32_16x16x32_bf16(pf, vf, acc[t], 0, 0, 0);
            }
        }
    }
    // normalize + write context (f32)
    #pragma unroll
    for(int j=0;j<4;++j){
        float rl = 1.0f / lrun[j];
        int row = zidx*256 + qt*64 + wid*16 + lg*4 + j;
        #pragma unroll
        for(int t=0;t<4;++t)
            ctx[(size_t)row*512 + h*64 + t*16 + l15] = acc[t][j] * rl;
    }
}

// ---------------------------------------------------------------------------
extern "C" void kernel_launch(void* const* d_in, const int* in_sizes, int n_in,
                              void* d_out, int out_size, void* d_ws, size_t ws_size,
                              hipStream_t stream){
    (void)in_sizes; (void)n_in; (void)out_size; (void)ws_size;
    const float* query     = (const float*)d_in[0];
    const float* key_value = (const float*)d_in[1];
    const float* query_pos = (const float*)d_in[2];
    const float* key_pos   = (const float*)d_in[3];
    const int*   key_mask  = (const int*)d_in[4];
    const float* Wq  = (const float*)d_in[5];
    const float* bq  = (const float*)d_in[6];
    const float* Wk  = (const float*)d_in[7];
    const float* bk  = (const float*)d_in[8];
    const float* Wv  = (const float*)d_in[9];
    const float* bv  = (const float*)d_in[10];
    const float* Wo  = (const float*)d_in[11];
    const float* bo  = (const float*)d_in[12];
    const float* Wqb = (const float*)d_in[13];
    const float* Wkb = (const float*)d_in[14];

    char* ws = (char*)d_ws;
    const size_t MB = 1048576;
    unsigned short* vp_kp = (unsigned short*)(ws);            // 32MB: vp, later kp
    unsigned short* vpT   = (unsigned short*)(ws + 32*MB);    // 32MB
    unsigned short* qp    = (unsigned short*)(ws + 64*MB);    //  8MB
    float*          biasb = (float*)(ws + 72*MB);             //  4MB
    float*          ctx   = (float*)(ws + 76*MB);             // 16MB
    unsigned short* WtQ   = (unsigned short*)(ws + 92*MB);    // 4 x 0.5MB
    unsigned short* WtK   = WtQ + 262144;
    unsigned short* WtV   = WtK + 262144;
    unsigned short* WtO   = WtV + 262144;

    wt_kernel<<<dim3(8,8), 256, 0, stream>>>(Wq, WtQ);
    wt_kernel<<<dim3(8,8), 256, 0, stream>>>(Wk, WtK);
    wt_kernel<<<dim3(8,8), 256, 0, stream>>>(Wv, WtV);
    wt_kernel<<<dim3(8,8), 256, 0, stream>>>(Wo, WtO);
    bias_kernel<<<4096, 256, 0, stream>>>(query_pos, key_pos, Wqb, Wkb, biasb);

    // V projection -> vp_kp, transpose to vpT, then K projection reuses vp_kp
    gemm512<true ><<<dim3(256,4), 256, 0, stream>>>(key_value, WtV, bv, vp_kp);
    vt_kernel<<<dim3(16,8,32), 256, 0, stream>>>(vp_kp, vpT);
    gemm512<true ><<<dim3(256,4), 256, 0, stream>>>(key_value, WtK, bk, vp_kp);
    gemm512<true ><<<dim3( 64,4), 256, 0, stream>>>(query, WtQ, bq, qp);

    attn_kernel<<<dim3(4,8,32), 256, 0, stream>>>(qp, vp_kp, vpT, biasb, key_mask, ctx);

    gemm512<false><<<dim3( 64,4), 256, 0, stream>>>(ctx, WtO, bo, d_out);
}

// Round 3
// 223.287 us; speedup vs baseline: 1.5354x; 1.5354x over previous
//
#include <hip/hip_runtime.h>
#include <hip/hip_bf16.h>
#include <stdint.h>

// Shapes (fixed): B=4, N=8, Q=256, K=1024, D_MODEL=512, H=8, Dh=64, R=8, sigma=0.05

typedef __attribute__((ext_vector_type(8))) short bf16x8;
typedef __attribute__((ext_vector_type(4))) float f32x4;

__device__ __forceinline__ unsigned short f2b(float f){
    unsigned int u = __builtin_bit_cast(unsigned int, f);
    unsigned int r = u + 0x7fffu + ((u >> 16) & 1u);   // RNE
    return (unsigned short)(r >> 16);
}

// XOR swizzle for 64-col bf16 LDS tiles (128B rows)
__device__ __forceinline__ int swz(int row, int byteInRow){
    return row*128 + (byteInRow ^ ((row & 7) << 4));
}
// Two-level swizzle for transpose tiles (row-writes AND column-reads OK)
__device__ __forceinline__ int swzT(int row, int byteInRow){
    return row*128 + (byteInRow ^ (((row ^ (row >> 3)) & 7) << 4));
}

// ---------------- all 4 weight transposes in one launch ---------------------
__global__ __launch_bounds__(256) void wt4_kernel(
    const float* __restrict__ Wq, const float* __restrict__ Wk,
    const float* __restrict__ Wv, const float* __restrict__ Wo,
    unsigned short* __restrict__ WtBase){   // 4 x [512][512]
    __shared__ float tile[64][65];
    int kt = blockIdx.x, nt = blockIdx.y, wsel = blockIdx.z;
    const float* W = (wsel == 0) ? Wq : (wsel == 1) ? Wk : (wsel == 2) ? Wv : Wo;
    unsigned short* Wt = WtBase + (size_t)wsel * 262144;
    int tid = threadIdx.x;
    #pragma unroll
    for(int it=0; it<16; ++it){
        int idx = it*256 + tid;
        int r = idx >> 6, c = idx & 63;
        tile[r][c] = W[(kt*64 + r)*512 + nt*64 + c];
    }
    __syncthreads();
    #pragma unroll
    for(int it=0; it<16; ++it){
        int idx = it*256 + tid;
        int r = idx >> 6, c = idx & 63;
        Wt[(nt*64 + r)*512 + kt*64 + c] = f2b(tile[c][r]);
    }
}

// ---------------- positional features (rank-3 collapsed bias) ---------------
// bias(q,k) [up to a per-q constant, softmax-invariant] =
//   qw . kp  +  (-200|kp|^2),  qw = qp^T (400 I + s * Wqb Wkb^T),  s = 1/sqrt(8)
// All values pre-multiplied by log2(e) so attn uses exp2.
__global__ __launch_bounds__(256) void posfeat_kernel(
    const float* __restrict__ qpos, const float* __restrict__ kpos,
    const float* __restrict__ Wqb,  const float* __restrict__ Wkb,
    const int* __restrict__ mask,
    float* __restrict__ qwg,        // [1024][4]
    float* __restrict__ kfg){       // [4096][4]
    const float L2E = 1.4426950408889634f;
    const float S8  = 0.35355339059327373f;
    int id = blockIdx.x*256 + threadIdx.x;   // 0..5119
    if(id < 1024){
        const float* p = qpos + id*3;
        float x = p[0], y = p[1], z = p[2];
        float qw0 = 400.f*x, qw1 = 400.f*y, qw2 = 400.f*z;
        #pragma unroll
        for(int r=0;r<8;++r){
            float qb = x*Wqb[r] + y*Wqb[8+r] + z*Wqb[16+r];
            float c  = S8*qb;
            qw0 += c*Wkb[r];
            qw1 += c*Wkb[8+r];
            qw2 += c*Wkb[16+r];
        }
        float4 o = {L2E*qw0, L2E*qw1, L2E*qw2, 0.f};
        *reinterpret_cast<float4*>(qwg + (size_t)id*4) = o;
    } else if(id < 5120){
        int k = id - 1024;
        const float* p = kpos + k*3;
        float x = p[0], y = p[1], z = p[2];
        float n2 = -200.0f*(x*x + y*y + z*z)*L2E;
        int mk = mask[k];
        float4 o = {x, y, z, mk ? n2 : -3.0e38f};
        *reinterpret_cast<float4*>(kfg + (size_t)k*4) = o;
    }
}

// ---------------- GEMM: C[M][512] = A[M][512] @ W + bias --------------------
// grid (n_tiles, m_tiles)  (n fastest for A-panel L2 reuse)
template<bool OUT_BF16, bool A_BF16>
__global__ __launch_bounds__(256) void gemm512(
    const void* __restrict__ Av,
    const unsigned short* __restrict__ Bt,
    const float* __restrict__ bias,
    void* __restrict__ Cv){
    __shared__ alignas(16) char sm[32768];
    char* As = sm;
    char* Bs = sm + 16384;
    int n0 = blockIdx.x * 128, m0 = blockIdx.y * 128;
    int tid = threadIdx.x;
    int l = tid & 63, wid = tid >> 6;
    int wr = wid >> 1, wc = wid & 1;
    int l15 = l & 15, lg = l >> 4;

    f32x4 acc[4][4];
    const f32x4 z4 = {0.f,0.f,0.f,0.f};
    #pragma unroll
    for(int m=0;m<4;++m)
        #pragma unroll
        for(int n=0;n<4;++n) acc[m][n] = z4;

    for(int kt=0; kt<8; ++kt){
        int k0 = kt*64;
        __syncthreads();
        if(A_BF16){
            const unsigned short* A = (const unsigned short*)Av;
            #pragma unroll
            for(int it=0; it<4; ++it){
                int idx = it*256 + tid;
                int row = idx >> 3;
                int colb = (idx & 7) * 16;
                uint4 v = *reinterpret_cast<const uint4*>(A + (size_t)(m0+row)*512 + k0 + colb/2);
                *reinterpret_cast<uint4*>(As + swz(row, colb)) = v;
            }
        } else {
            const float* A = (const float*)Av;
            #pragma unroll
            for(int it=0; it<8; ++it){
                int idx = it*256 + tid;
                int row = idx >> 4;
                int col = (idx & 15) * 4;
                float4 v = *reinterpret_cast<const float4*>(A + (size_t)(m0+row)*512 + k0 + col);
                uint2 d;
                d.x = (unsigned)f2b(v.x) | ((unsigned)f2b(v.y) << 16);
                d.y = (unsigned)f2b(v.z) | ((unsigned)f2b(v.w) << 16);
                *reinterpret_cast<uint2*>(As + swz(row, col*2)) = d;
            }
        }
        #pragma unroll
        for(int it=0; it<4; ++it){
            int idx = it*256 + tid;
            int row = idx >> 3;
            int colb = (idx & 7) * 16;
            uint4 v = *reinterpret_cast<const uint4*>(Bt + (size_t)(n0+row)*512 + k0 + colb/2);
            *reinterpret_cast<uint4*>(Bs + swz(row, colb)) = v;
        }
        __syncthreads();
        #pragma unroll
        for(int kk=0; kk<2; ++kk){
            bf16x8 af[4], bfr[4];
            #pragma unroll
            for(int m=0;m<4;++m)
                af[m] = *reinterpret_cast<const bf16x8*>(As + swz(wr*64 + m*16 + l15, kk*64 + lg*16));
            #pragma unroll
            for(int n=0;n<4;++n)
                bfr[n] = *reinterpret_cast<const bf16x8*>(Bs + swz(wc*64 + n*16 + l15, kk*64 + lg*16));
            #pragma unroll
            for(int m=0;m<4;++m)
                #pragma unroll
                for(int n=0;n<4;++n)
                    acc[m][n] = __builtin_amdgcn_mfma_f32_16x16x32_bf16(af[m], bfr[n], acc[m][n], 0, 0, 0);
        }
    }
    #pragma unroll
    for(int m=0;m<4;++m){
        int row = m0 + wr*64 + m*16 + lg*4;
        #pragma unroll
        for(int n=0;n<4;++n){
            int col = n0 + wc*64 + n*16 + l15;
            float bv = bias[col];
            #pragma unroll
            for(int j=0;j<4;++j){
                float val = acc[m][n][j] + bv;
                if(OUT_BF16)
                    reinterpret_cast<unsigned short*>(Cv)[(size_t)(row+j)*512 + col] = f2b(val);
                else
                    reinterpret_cast<float*>(Cv)[(size_t)(row+j)*512 + col] = val;
            }
        }
    }
}

// ---------------- V transpose: vp[z*1024+k][h*64+d] -> vpT[(z*8+h)*64+d][k] -
__global__ __launch_bounds__(256) void vt_kernel(const unsigned short* __restrict__ vp,
                                                 unsigned short* __restrict__ vpT){
    __shared__ alignas(16) char sm[8192];
    int kt = blockIdx.x, h = blockIdx.y, z = blockIdx.z;
    int tid = threadIdx.x;
    #pragma unroll
    for(int it=0; it<2; ++it){
        int idx = it*256 + tid;
        int r = idx >> 3;
        int c8 = idx & 7;
        uint4 v = *reinterpret_cast<const uint4*>(vp + (size_t)(z*1024 + kt*64 + r)*512 + h*64 + c8*8);
        *reinterpret_cast<uint4*>(sm + swzT(r, c8*16)) = v;
    }
    __syncthreads();
    #pragma unroll
    for(int it=0; it<2; ++it){
        int idx = it*256 + tid;
        int d = idx >> 3;
        int k8 = idx & 7;
        unsigned short e[8];
        #pragma unroll
        for(int j=0;j<8;++j)
            e[j] = *reinterpret_cast<const unsigned short*>(sm + swzT(k8*8+j, d*2));
        *reinterpret_cast<uint4*>(vpT + (size_t)((z*8+h)*64 + d)*1024 + kt*64 + k8*8) = *reinterpret_cast<uint4*>(e);
    }
}

// ---------------- attention: 1 block per (z, h, q-half), 8 waves ------------
__global__ __launch_bounds__(512) void attn2_kernel(
    const unsigned short* __restrict__ qp,   // [8192][512] bf16
    const unsigned short* __restrict__ kp,   // [32768][512] bf16
    const unsigned short* __restrict__ vpT,  // [16384][1024] bf16
    const float* __restrict__ qwg,           // [1024][4] L2E-folded
    const float* __restrict__ kfg,           // [4096][4] L2E-folded
    unsigned short* __restrict__ ctxb){      // [8192][512] bf16
    __shared__ alignas(16) char sm[33792];
    char* Ks  = sm;            // [64 k][64 d] swizzled
    char* VTs = sm + 8192;     // [64 d][64 k] swizzled
    char* kfs = sm + 16384;    // [64 k][4 f32]
    char* Ps  = sm + 17408;    // per-wave 2048B

    const float SCALE2 = 0.18033688011112042f;   // 0.125 * log2(e)

    int bid = blockIdx.x;
    int wg  = (bid & 7)*64 + (bid >> 3);         // XCD-chunked bijection (512 = 8*64)
    int qs = wg & 1, h = (wg >> 1) & 7, z = wg >> 4;
    int b = z >> 3;
    int tid = threadIdx.x, l = tid & 63, wid = tid >> 6;
    int l15 = l & 15, lg = l >> 4;
    int srow = tid >> 3, sc8 = tid & 7;

    const unsigned short* kbase = kp  + (size_t)(z*1024)*512 + h*64;
    const unsigned short* vbase = vpT + (size_t)((z*8+h)*64)*1024;

    // Q fragments (16 q-rows per wave)
    int qrow = z*256 + qs*128 + wid*16 + l15;
    bf16x8 qf[2];
    #pragma unroll
    for(int kk=0;kk<2;++kk)
        qf[kk] = *reinterpret_cast<const bf16x8*>(qp + (size_t)qrow*512 + h*64 + kk*32 + lg*8);

    // per-row bias weights, rows lg*4+j (C layout)
    f32x4 qwr[4];
    #pragma unroll
    for(int j=0;j<4;++j)
        qwr[j] = *reinterpret_cast<const f32x4*>(qwg + (size_t)(b*256 + qs*128 + wid*16 + lg*4 + j)*4);

    float mrun[4], lrun[4];
    f32x4 acc[4];
    const f32x4 z4 = {0.f,0.f,0.f,0.f};
    #pragma unroll
    for(int j=0;j<4;++j){ mrun[j] = -3.0e38f; lrun[j] = 0.f; }
    #pragma unroll
    for(int t=0;t<4;++t) acc[t] = z4;

    // prefetch tile 0
    uint4 kreg, vreg, freg;
    kreg = *reinterpret_cast<const uint4*>(kbase + (size_t)srow*512 + sc8*8);
    vreg = *reinterpret_cast<const uint4*>(vbase + (size_t)srow*1024 + sc8*8);
    if(tid < 64) freg = *reinterpret_cast<const uint4*>(kfg + (size_t)(b*1024 + tid)*4);

    for(int kt=0; kt<16; ++kt){
        __syncthreads();
        *reinterpret_cast<uint4*>(Ks  + swz(srow, sc8*16)) = kreg;
        *reinterpret_cast<uint4*>(VTs + swz(srow, sc8*16)) = vreg;
        if(tid < 64) *reinterpret_cast<uint4*>(kfs + tid*16) = freg;
        __syncthreads();
        if(kt < 15){
            kreg = *reinterpret_cast<const uint4*>(kbase + (size_t)((kt+1)*64 + srow)*512 + sc8*8);
            vreg = *reinterpret_cast<const uint4*>(vbase + (size_t)srow*1024 + (kt+1)*64 + sc8*8);
            if(tid < 64) freg = *reinterpret_cast<const uint4*>(kfg + (size_t)(b*1024 + (kt+1)*64 + tid)*4);
        }

        // S = q @ K^T
        f32x4 s[4];
        #pragma unroll
        for(int t=0;t<4;++t){
            s[t] = z4;
            #pragma unroll
            for(int kk=0;kk<2;++kk){
                bf16x8 kf = *reinterpret_cast<const bf16x8*>(Ks + swz(t*16 + l15, kk*64 + lg*16));
                s[t] = __builtin_amdgcn_mfma_f32_16x16x32_bf16(qf[kk], kf, s[t], 0, 0, 0);
            }
        }
        // bias (rank-3 + |k|^2 term, base-2 domain), mask folded into kv[3]
        #pragma unroll
        for(int t=0;t<4;++t){
            f32x4 kv = *reinterpret_cast<const f32x4*>(kfs + (t*16 + l15)*16);
            #pragma unroll
            for(int j=0;j<4;++j){
                float bias = kv[3] + qwr[j][0]*kv[0] + qwr[j][1]*kv[1] + qwr[j][2]*kv[2];
                s[t][j] = s[t][j]*SCALE2 + bias;
            }
        }
        // online softmax (base 2)
        float pmax[4];
        #pragma unroll
        for(int j=0;j<4;++j){
            float mx = fmaxf(fmaxf(s[0][j], s[1][j]), fmaxf(s[2][j], s[3][j]));
            mx = fmaxf(mx, __shfl_xor(mx, 1, 16));
            mx = fmaxf(mx, __shfl_xor(mx, 2, 16));
            mx = fmaxf(mx, __shfl_xor(mx, 4, 16));
            mx = fmaxf(mx, __shfl_xor(mx, 8, 16));
            pmax[j] = mx;
        }
        float scl[4];
        #pragma unroll
        for(int j=0;j<4;++j){
            float mn = fmaxf(mrun[j], pmax[j]);
            scl[j] = exp2f(mrun[j] - mn);
            mrun[j] = mn;
        }
        float psum[4] = {0.f,0.f,0.f,0.f};
        unsigned short pb[4][4];
        #pragma unroll
        for(int t=0;t<4;++t)
            #pragma unroll
            for(int j=0;j<4;++j){
                float p = exp2f(s[t][j] - mrun[j]);
                psum[j] += p;
                pb[t][j] = f2b(p);
            }
        #pragma unroll
        for(int j=0;j<4;++j){
            float ps = psum[j];
            ps += __shfl_xor(ps, 1, 16);
            ps += __shfl_xor(ps, 2, 16);
            ps += __shfl_xor(ps, 4, 16);
            ps += __shfl_xor(ps, 8, 16);
            lrun[j] = lrun[j]*scl[j] + ps;
            #pragma unroll
            for(int t=0;t<4;++t) acc[t][j] *= scl[j];
        }
        // P -> per-wave LDS (wave-local, no block barrier)
        char* Pw = Ps + wid*2048;
        #pragma unroll
        for(int t=0;t<4;++t)
            #pragma unroll
            for(int j=0;j<4;++j)
                *reinterpret_cast<unsigned short*>(Pw + swz(lg*4 + j, (t*16 + l15)*2)) = pb[t][j];
        // PV
        #pragma unroll
        for(int kk=0;kk<2;++kk){
            bf16x8 pf = *reinterpret_cast<const bf16x8*>(Pw + swz(l15, kk*64 + lg*16));
            #pragma unroll
            for(int t=0;t<4;++t){
                bf16x8 vf = *reinterpret_cast<const bf16x8*>(VTs + swz(t*16 + l15, kk*64 + lg*16));
                acc[t] = __builtin_amdgcn_mfma_f32_16x16x32_bf16(pf, vf, acc[t], 0, 0, 0);
            }
        }
    }
    // normalize + write context (bf16)
    #pragma unroll
    for(int j=0;j<4;++j){
        float rl = 1.0f / lrun[j];
        int row = z*256 + qs*128 + wid*16 + lg*4 + j;
        #pragma unroll
        for(int t=0;t<4;++t)
            ctxb[(size_t)row*512 + h*64 + t*16 + l15] = f2b(acc[t][j] * rl);
    }
}

// ---------------------------------------------------------------------------
extern "C" void kernel_launch(void* const* d_in, const int* in_sizes, int n_in,
                              void* d_out, int out_size, void* d_ws, size_t ws_size,
                              hipStream_t stream){
    (void)in_sizes; (void)n_in; (void)out_size; (void)ws_size;
    const float* query     = (const float*)d_in[0];
    const float* key_value = (const float*)d_in[1];
    const float* query_pos = (const float*)d_in[2];
    const float* key_pos   = (const float*)d_in[3];
    const int*   key_mask  = (const int*)d_in[4];
    const float* Wq  = (const float*)d_in[5];
    const float* bq  = (const float*)d_in[6];
    const float* Wk  = (const float*)d_in[7];
    const float* bk  = (const float*)d_in[8];
    const float* Wv  = (const float*)d_in[9];
    const float* bv  = (const float*)d_in[10];
    const float* Wo  = (const float*)d_in[11];
    const float* bo  = (const float*)d_in[12];
    const float* Wqb = (const float*)d_in[13];
    const float* Wkb = (const float*)d_in[14];

    char* ws = (char*)d_ws;
    const size_t MB = 1048576;
    unsigned short* vp_kp = (unsigned short*)(ws);            // 32MB: vp, later kp
    unsigned short* vpT   = (unsigned short*)(ws + 32*MB);    // 32MB
    unsigned short* qp    = (unsigned short*)(ws + 64*MB);    //  8MB
    unsigned short* ctxb  = (unsigned short*)(ws + 72*MB);    //  8MB
    unsigned short* WtQ   = (unsigned short*)(ws + 80*MB);    // 4 x 0.5MB
    unsigned short* WtK   = WtQ + 262144;
    unsigned short* WtV   = WtK + 262144;
    unsigned short* WtO   = WtV + 262144;
    float*          qwg   = (float*)(ws + 82*MB);             // 16KB
    float*          kfg   = (float*)(ws + 82*MB + 65536);     // 64KB

    wt4_kernel<<<dim3(8,8,4), 256, 0, stream>>>(Wq, Wk, Wv, Wo, WtQ);
    posfeat_kernel<<<20, 256, 0, stream>>>(query_pos, key_pos, Wqb, Wkb, key_mask, qwg, kfg);

    // V projection -> vp, transpose -> vpT, then K projection reuses the buffer
    gemm512<true ,false><<<dim3(4,256), 256, 0, stream>>>(key_value, WtV, bv, vp_kp);
    vt_kernel<<<dim3(16,8,32), 256, 0, stream>>>(vp_kp, vpT);
    gemm512<true ,false><<<dim3(4,256), 256, 0, stream>>>(key_value, WtK, bk, vp_kp);
    gemm512<true ,false><<<dim3(4, 64), 256, 0, stream>>>(query, WtQ, bq, qp);

    attn2_kernel<<<512, 512, 0, stream>>>(qp, vp_kp, vpT, qwg, kfg, ctxb);

    gemm512<false,true ><<<dim3(4, 64), 256, 0, stream>>>(ctxb, WtO, bo, d_out);
}